// Round 3
// baseline (194.908 us; speedup 1.0000x reference)
//
#include <hip/hip_runtime.h>
#include <hip/hip_bf16.h>

// CrossAttention MI355X — Round 13.
//  - Both GEMMs: T3-minimal double-buffered LDS staging — stage tile t+1
//    (global_load_lds) BEFORE computing tile t; single barrier per K-step
//    drains DMAs that had the whole compute phase in flight. Was: stage +
//    drain back-to-back (full L2/L3 latency exposed 16x per block).
//  - gemm_proj back to 64x64 tile (R12's 128x64 @ 512 blocks = 2/CU lost
//    TLP and regressed ~7us); dbuf LDS 32 KB -> 5 blocks/CU.
//  - T1 bijective chunked XCD swizzle on gemm_qk / gemm_proj / attn so
//    blocks sharing A-/K-panels land on one XCD's L2 (chunks ~3-4 MB).
//  - attn v7 = v6 (T14 reg prefetch + cvt_pk pack) + T1 remap only.
// Reference quirk: k = v = kv[:,:,0] -> only W_kv rows [0,1024) matter.

typedef __bf16 bf16x8 __attribute__((ext_vector_type(8)));
typedef float f32x4 __attribute__((ext_vector_type(4)));
typedef float f32x16 __attribute__((ext_vector_type(16)));

static constexpr int kDIM = 1024;
static constexpr float kLog2e = 1.4426950408889634f;

__device__ inline unsigned short f2bf(float f) {      // RNE
    union { float f; unsigned int u; } v; v.f = f;
    return (unsigned short)((v.u + 0x7FFFu + ((v.u >> 16) & 1u)) >> 16);
}

// single-instruction bf16 pair-pack: low16 = bf16(a), high16 = bf16(b)
__device__ inline unsigned int cvtpk2bf(float a, float b) {
    unsigned int r;
    asm("v_cvt_pk_bf16_f32 %0, %1, %2" : "=v"(r) : "v"(a), "v"(b));
    return r;
}

// async global->LDS, 16 B per lane; LDS dest = wave-uniform base + lane*16
__device__ inline void gload_lds16(const unsigned short* g, unsigned short* l) {
    __builtin_amdgcn_global_load_lds(
        (const __attribute__((address_space(1))) unsigned int*)g,
        (__attribute__((address_space(3))) unsigned int*)l, 16, 0, 0);
}

// ---------------------------------------------------------------------------
// Single cast kernel (unchanged).
// ---------------------------------------------------------------------------
__global__ __launch_bounds__(256) void cast_all(
    const float* __restrict__ x, const float* __restrict__ ctx,
    const float* __restrict__ wq, const float* __restrict__ wkv,
    const float* __restrict__ wp,
    unsigned short* __restrict__ xb, unsigned short* __restrict__ cb,
    unsigned short* __restrict__ wqb, unsigned short* __restrict__ wkb,
    unsigned short* __restrict__ wpb)
{
    int j = blockIdx.x * 256 + threadIdx.x;   // float4 index
    const float* s; unsigned short* d;
    if (j < 1048576)                      { s = x;   d = xb;  }
    else if ((j -= 1048576) < 1048576)    { s = ctx; d = cb;  }
    else if ((j -= 1048576) < 262144)     { s = wq;  d = wqb; }
    else if ((j -= 262144) < 262144)      { s = wkv; d = wkb; }
    else if ((j -= 262144) < 262144)      { s = wp;  d = wpb; }
    else return;
    float4 f = ((const float4*)s)[j];
    ushort4 o;
    o.x = f2bf(f.x); o.y = f2bf(f.y); o.z = f2bf(f.z); o.w = f2bf(f.w);
    ((ushort4*)d)[j] = o;
}

// ---------------------------------------------------------------------------
// Fused Q/K projection GEMM: 128(m)x64(n) tile, 256 thr (2x2 waves of 64x32),
// BK=64, double-buffered XOR-swizzled global_load_lds staging, T1 XCD remap.
// grid (16,32,2) = 1024 blocks; LDS 48 KB -> 3 blocks/CU.
// z=0: Qb = qscale * x @ Wq^T ; z=1: Kb = ctx @ Wkv^T (+ K^T layout Ktb).
// LDS layout: elem(row, physcg*8..+7), physcg = logicalcg ^ (row&7).
// ---------------------------------------------------------------------------
__global__ __launch_bounds__(256, 4) void gemm_qk(
    const unsigned short* __restrict__ xb, const unsigned short* __restrict__ cb,
    const unsigned short* __restrict__ Wq, const unsigned short* __restrict__ Wkv,
    unsigned short* __restrict__ Qb, unsigned short* __restrict__ Kb,
    unsigned short* __restrict__ Ktb, float qscale, int Mctx)
{
    __shared__ unsigned short As[2 * 128 * 64];
    __shared__ unsigned short Bs[2 * 64 * 64];

    // T1: bijective chunked XCD remap (1024 blocks, chunk = 128/XCD).
    const int lin  = blockIdx.x + 16 * blockIdx.y + 512 * blockIdx.z;
    const int orig = (lin & 7) * 128 + (lin >> 3);
    const int bxi  = orig & 15;
    const int byi  = (orig >> 4) & 31;
    const int z    = orig >> 9;

    const unsigned short* A  = z ? cb : xb;
    const unsigned short* Bw = z ? Wkv : Wq;
    unsigned short* Cb = z ? Kb : Qb;
    const float scale = z ? 1.0f : qscale;

    const int tid = threadIdx.x;
    const int wave = tid >> 6, lane = tid & 63;
    const int g = lane >> 4, c = lane & 15;
    const int wm = (wave & 1) * 64, wn = (wave >> 1) * 32;
    const int bm = byi * 128, bn = bxi * 64;

    const int srow = lane >> 3;
    const int scolsw = ((lane & 7) ^ (srow & 7)) * 8;   // swizzled source col
    const int x7 = c & 7;                               // frag-read XOR term

    f32x4 acc[4][2];
    #pragma unroll
    for (int i = 0; i < 4; ++i)
        #pragma unroll
        for (int j = 0; j < 2; ++j)
            acc[i][j] = (f32x4){0.f, 0.f, 0.f, 0.f};

    auto stage = [&](int buf, int k0) {
        unsigned short* Ad = As + buf * (128 * 64);
        unsigned short* Bd = Bs + buf * (64 * 64);
        #pragma unroll
        for (int t = 0; t < 4; ++t) {                 // A: 16 chunks
            const int chunk = wave * 4 + t;
            gload_lds16(A + (size_t)(bm + chunk * 8 + srow) * kDIM + k0 + scolsw,
                        Ad + chunk * 512);
        }
        #pragma unroll
        for (int t = 0; t < 2; ++t) {                 // B: 8 chunks
            const int chunk = wave * 2 + t;
            gload_lds16(Bw + (size_t)(bn + chunk * 8 + srow) * kDIM + k0 + scolsw,
                        Bd + chunk * 512);
        }
    };

    stage(0, 0);
    __syncthreads();                                  // tile 0 resident

    for (int t = 0; t < 16; ++t) {
        const int cur = t & 1;
        if (t < 15) stage(cur ^ 1, (t + 1) * 64);     // issue next tile's DMA
        const unsigned short* Ac = As + cur * (128 * 64);
        const unsigned short* Bc = Bs + cur * (64 * 64);
        #pragma unroll
        for (int kc = 0; kc < 2; ++kc) {
            bf16x8 af[4], bfr[2];
            #pragma unroll
            for (int i = 0; i < 4; ++i)
                af[i] = *(const bf16x8*)&Ac[(wm + i * 16 + c) * 64 +
                                            ((kc * 4 + g) ^ x7) * 8];
            #pragma unroll
            for (int j = 0; j < 2; ++j)
                bfr[j] = *(const bf16x8*)&Bc[(wn + j * 16 + c) * 64 +
                                             ((kc * 4 + g) ^ x7) * 8];
            #pragma unroll
            for (int i = 0; i < 4; ++i)
                #pragma unroll
                for (int j = 0; j < 2; ++j)
                    acc[i][j] = __builtin_amdgcn_mfma_f32_16x16x32_bf16(
                        af[i], bfr[j], acc[i][j], 0, 0, 0);
        }
        __syncthreads();    // drains this iter's DMA (in flight during MFMA)
    }

    #pragma unroll
    for (int i = 0; i < 4; ++i) {
        #pragma unroll
        for (int j = 0; j < 2; ++j) {
            const int r0 = bm + wm + i * 16 + 4 * g;
            const int cc = bn + wn + j * 16 + c;
            float v0 = acc[i][j][0] * scale;
            float v1 = acc[i][j][1] * scale;
            float v2 = acc[i][j][2] * scale;
            float v3 = acc[i][j][3] * scale;
            Cb[(size_t)(r0 + 0) * kDIM + cc] = f2bf(v0);
            Cb[(size_t)(r0 + 1) * kDIM + cc] = f2bf(v1);
            Cb[(size_t)(r0 + 2) * kDIM + cc] = f2bf(v2);
            Cb[(size_t)(r0 + 3) * kDIM + cc] = f2bf(v3);
            if (z) {
                const int bb = r0 / Mctx, n0 = r0 % Mctx;
                const int hh = cc >> 6, d = cc & 63;
                ushort4 pk;
                pk.x = f2bf(v0); pk.y = f2bf(v1); pk.z = f2bf(v2); pk.w = f2bf(v3);
                *(ushort4*)&Ktb[((size_t)((bb * 16 + hh) * 64 + d)) * Mctx + n0] = pk;
            }
        }
    }
}

// ---------------------------------------------------------------------------
// Proj GEMM: 64x64 tiles (R10 shape), grid (16,64) = 1024 blocks, 256 thr,
// BK=64, double-buffered DMA staging (LDS 32 KB -> 5 blocks/CU), T1 remap.
// ---------------------------------------------------------------------------
__global__ __launch_bounds__(256, 4) void gemm_proj(
    const unsigned short* __restrict__ Ab, const unsigned short* __restrict__ Wp,
    const float* __restrict__ bias, float* __restrict__ out)
{
    __shared__ unsigned short As[2 * 64 * 64];
    __shared__ unsigned short Bs[2 * 64 * 64];

    // T1: bijective chunked XCD remap (1024 blocks, chunk = 128/XCD).
    const int lin  = blockIdx.x + 16 * blockIdx.y;
    const int orig = (lin & 7) * 128 + (lin >> 3);
    const int bm = (orig >> 4) * 64, bn = (orig & 15) * 64;

    const int tid = threadIdx.x;
    const int wave = tid >> 6, lane = tid & 63;
    const int g = lane >> 4, c = lane & 15;
    const int wm = (wave & 1) * 32, wn = (wave >> 1) * 32;

    const int srow = lane >> 3;
    const int scolsw = ((lane & 7) ^ (srow & 7)) * 8;
    const int x7 = c & 7;

    f32x4 acc[2][2];
    #pragma unroll
    for (int i = 0; i < 2; ++i)
        #pragma unroll
        for (int j = 0; j < 2; ++j)
            acc[i][j] = (f32x4){0.f, 0.f, 0.f, 0.f};

    auto stage = [&](int buf, int k0) {
        unsigned short* Ad = As + buf * (64 * 64);
        unsigned short* Bd = Bs + buf * (64 * 64);
        #pragma unroll
        for (int t = 0; t < 2; ++t) {
            const int chunk = wave * 2 + t;              // 0..7
            const int row = chunk * 8 + srow;
            gload_lds16(Ab + (size_t)(bm + row) * kDIM + k0 + scolsw, Ad + chunk * 512);
            gload_lds16(Wp + (size_t)(bn + row) * kDIM + k0 + scolsw, Bd + chunk * 512);
        }
    };

    stage(0, 0);
    __syncthreads();

    for (int t = 0; t < 16; ++t) {
        const int cur = t & 1;
        if (t < 15) stage(cur ^ 1, (t + 1) * 64);
        const unsigned short* Ac = As + cur * (64 * 64);
        const unsigned short* Bc = Bs + cur * (64 * 64);
        #pragma unroll
        for (int kc = 0; kc < 2; ++kc) {
            bf16x8 af[2], bfr[2];
            #pragma unroll
            for (int i = 0; i < 2; ++i)
                af[i] = *(const bf16x8*)&Ac[(wm + i * 16 + c) * 64 +
                                            ((kc * 4 + g) ^ x7) * 8];
            #pragma unroll
            for (int j = 0; j < 2; ++j)
                bfr[j] = *(const bf16x8*)&Bc[(wn + j * 16 + c) * 64 +
                                             ((kc * 4 + g) ^ x7) * 8];
            #pragma unroll
            for (int i = 0; i < 2; ++i)
                #pragma unroll
                for (int j = 0; j < 2; ++j)
                    acc[i][j] = __builtin_amdgcn_mfma_f32_16x16x32_bf16(
                        af[i], bfr[j], acc[i][j], 0, 0, 0);
        }
        __syncthreads();
    }

    #pragma unroll
    for (int i = 0; i < 2; ++i) {
        #pragma unroll
        for (int j = 0; j < 2; ++j) {
            const int r0 = bm + wm + i * 16 + 4 * g;
            const int cc = bn + wn + j * 16 + c;
            const float bv = bias[cc];
            #pragma unroll
            for (int ii = 0; ii < 4; ++ii)
                out[(size_t)(r0 + ii) * kDIM + cc] = acc[i][j][ii] + bv;
        }
    }
}

// ---------------------------------------------------------------------------
// Flash attention v7: v6 (T14 reg prefetch of next K/Kt tile + cvt_pk P
// packing) + T1 XCD remap so the 16 q-blocks sharing a (b,h) K-panel land
// on one XCD's L2. 512 threads = 8 waves = 4 q-strips x 2 key-halves.
// 32x32x16 MFMA, S^T layout, P via padded-72 LDS, key-half merge at end.
// ---------------------------------------------------------------------------
__global__ __launch_bounds__(512, 4) void attn_mfma_v7(
    const unsigned short* __restrict__ Q,   // [B*N][1024]
    const unsigned short* __restrict__ K,   // [B*M][1024]
    const unsigned short* __restrict__ Kt,  // [(B*16+h)*64+d][M]
    unsigned short* __restrict__ O, int N, int M)
{
    __shared__ unsigned short smem[18432];        // 36,864 B
    unsigned short* Ks  = smem;                   // [64][72]
    unsigned short* Kts = smem + 64 * 72;         // [64][72]
    unsigned short* Ps  = smem + 2 * 64 * 72;     // [128][72]

    // T1: bijective chunked XCD remap (512 blocks, chunk = 64/XCD).
    const int lin  = blockIdx.x + 16 * (blockIdx.y + 16 * blockIdx.z);
    const int orig = (lin & 7) * 64 + (lin >> 3);
    const int q0 = (orig & 15) * 128;
    const int h  = (orig >> 4) & 15;
    const int b  = orig >> 8;

    const int tid = threadIdx.x;
    const int w = tid >> 6, lane = tid & 63;
    const int strip = w >> 1, kh = w & 1;
    const int ql = lane & 31, l5 = lane >> 5;

    const unsigned short* Qrow = Q + (size_t)(b * N + q0 + strip * 32 + ql) * kDIM + h * 64;
    const unsigned short* Kb = K + (size_t)b * M * kDIM + h * 64;
    const unsigned short* Ktb = Kt + (size_t)((b * 16 + h) * 64) * M;

    bf16x8 bq[4];
    #pragma unroll
    for (int kc = 0; kc < 4; ++kc)
        bq[kc] = *(const bf16x8*)(Qrow + kc * 16 + l5 * 8);

    f32x16 ot[2];
    #pragma unroll
    for (int dt = 0; dt < 2; ++dt)
        #pragma unroll
        for (int r = 0; r < 16; ++r) ot[dt][r] = 0.f;
    float lac = 0.f;

    const int srow = tid >> 3, scol = (tid & 7) * 8;
    unsigned short* prow = &Ps[(strip * 32 + ql) * 72 + kh * 32];

    // T14: prefetch first K/Kt tile into registers before the loop.
    uint4 rk  = *(const uint4*)(Kb  + (size_t)srow * kDIM + scol);
    uint4 rkt = *(const uint4*)(Ktb + (size_t)srow * M + scol);

    for (int k0 = 0; k0 < M; k0 += 64) {
        __syncthreads();                          // prev-iter LDS reads done
        *(uint4*)&Ks[srow * 72 + scol]  = rk;
        *(uint4*)&Kts[srow * 72 + scol] = rkt;
        __syncthreads();

        // Issue next tile's global loads now; latency hides under compute.
        if (k0 + 64 < M) {
            rk  = *(const uint4*)(Kb  + (size_t)(k0 + 64 + srow) * kDIM + scol);
            rkt = *(const uint4*)(Ktb + (size_t)srow * M + (k0 + 64) + scol);
        }

        // S^T (32 keys of this wave's half x 32 q): A = K, B = Q.
        f32x16 st;
        #pragma unroll
        for (int r = 0; r < 16; ++r) st[r] = 0.f;
        #pragma unroll
        for (int kc = 0; kc < 4; ++kc) {
            bf16x8 ak = *(const bf16x8*)&Ks[(kh * 32 + ql) * 72 + kc * 16 + l5 * 8];
            st = __builtin_amdgcn_mfma_f32_32x32x16_bf16(ak, bq[kc], st, 0, 0, 0);
        }

        // p = 2^s; per-lane partial row sums; pack key-pairs; b64 Ps writes.
        float pr[16];
        #pragma unroll
        for (int r = 0; r < 16; ++r) {
            pr[r] = __builtin_amdgcn_exp2f(st[r]);
            lac += pr[r];
        }
        unsigned int dw[8];
        #pragma unroll
        for (int p = 0; p < 8; ++p) dw[p] = cvtpk2bf(pr[2 * p], pr[2 * p + 1]);
        #pragma unroll
        for (int pp = 0; pp < 4; ++pp)
            *(uint2*)&prow[8 * pp + 4 * l5] = make_uint2(dw[2 * pp], dw[2 * pp + 1]);
        // wave-private Ps rows/cols: no barrier needed

        // O^T += V^T . P  (A = V^T from Kts, B = P from Ps)
        #pragma unroll
        for (int kc2 = 0; kc2 < 2; ++kc2) {
            bf16x8 bp = *(const bf16x8*)&prow[kc2 * 16 + l5 * 8];
            #pragma unroll
            for (int dt = 0; dt < 2; ++dt) {
                bf16x8 av = *(const bf16x8*)&Kts[(dt * 32 + ql) * 72 + kh * 32 + kc2 * 16 + l5 * 8];
                ot[dt] = __builtin_amdgcn_mfma_f32_32x32x16_bf16(av, bp, ot[dt], 0, 0, 0);
            }
        }
    }

    // Merge the two key-halves via LDS, normalize, store.
    float lw = lac + __shfl_xor(lac, 32);     // full half-sum for this q
    float* Om = (float*)smem;                  // [128][68] fp32
    float* Lm = Om + 128 * 68;                 // [128]
    const int qi = strip * 32 + ql;

    __syncthreads();                           // all LDS reads of last iter done
    if (kh == 1) {
        #pragma unroll
        for (int dt = 0; dt < 2; ++dt)
            #pragma unroll
            for (int rr = 0; rr < 4; ++rr)
                *(f32x4*)&Om[qi * 68 + dt * 32 + 8 * rr + 4 * l5] =
                    (f32x4){ot[dt][4 * rr], ot[dt][4 * rr + 1],
                            ot[dt][4 * rr + 2], ot[dt][4 * rr + 3]};
        if (l5 == 0) Lm[qi] = lw;
    }
    __syncthreads();
    if (kh == 0) {
        const float inv = 1.0f / (lw + Lm[qi]);
        unsigned short* Ob = O + (size_t)(b * N + q0 + qi) * kDIM + h * 64;
        #pragma unroll
        for (int dt = 0; dt < 2; ++dt)
            #pragma unroll
            for (int rr = 0; rr < 4; ++rr) {
                f32x4 pv = *(const f32x4*)&Om[qi * 68 + dt * 32 + 8 * rr + 4 * l5];
                ushort4 u;
                u.x = f2bf((ot[dt][4 * rr]     + pv[0]) * inv);
                u.y = f2bf((ot[dt][4 * rr + 1] + pv[1]) * inv);
                u.z = f2bf((ot[dt][4 * rr + 2] + pv[2]) * inv);
                u.w = f2bf((ot[dt][4 * rr + 3] + pv[3]) * inv);
                *(ushort4*)(Ob + dt * 32 + 8 * rr + 4 * l5) = u;
            }
    }
}

// ---------------------------------------------------------------------------
extern "C" void kernel_launch(void* const* d_in, const int* in_sizes, int n_in,
                              void* d_out, int out_size, void* d_ws, size_t ws_size,
                              hipStream_t stream)
{
    const float* x      = (const float*)d_in[0];
    const float* ctxp   = (const float*)d_in[1];
    const float* W_q    = (const float*)d_in[2];
    const float* W_kv   = (const float*)d_in[3];
    const float* W_proj = (const float*)d_in[4];
    const float* b_proj = (const float*)d_in[5];
    float* out = (float*)d_out;

    const int B = 2, N = 2048, M = 2048;
    const int BN = B * N;        // 4096
    const int SQ = kDIM * kDIM;  // 1M

    unsigned short* p = (unsigned short*)d_ws;
    unsigned short* xb  = p; p += (size_t)BN * kDIM;   // reused as Ab
    unsigned short* cb  = p; p += (size_t)BN * kDIM;
    unsigned short* wqb = p; p += SQ;
    unsigned short* wkb = p; p += SQ;
    unsigned short* wpb = p; p += SQ;
    unsigned short* Qb  = p; p += (size_t)BN * kDIM;
    unsigned short* Kb  = p; p += (size_t)BN * kDIM;
    unsigned short* Ktb = p; p += (size_t)BN * kDIM;
    unsigned short* Ab  = xb;    // xb dead after gemm_qk

    // 1) fp32 -> bf16 for all inputs
    hipLaunchKernelGGL(cast_all, dim3(11264), dim3(256), 0, stream,
                       x, ctxp, W_q, W_kv, W_proj, xb, cb, wqb, wkb, wpb);
    // 2) z=0: Q = (0.125*log2e) * x @ Wq^T ; z=1: K(=V) = ctx @ Wkv^T (+ K^T)
    hipLaunchKernelGGL(gemm_qk, dim3(kDIM / 64, BN / 128, 2), dim3(256), 0, stream,
                       xb, cb, wqb, wkb, Qb, Kb, Ktb, 0.125f * kLog2e, M);
    // 3) A = softmax(Q K^T) V
    hipLaunchKernelGGL(attn_mfma_v7, dim3(N / 128, 16, B), dim3(512), 0, stream,
                       Qb, Kb, Ktb, Ab, N, M);
    // 4) out = A @ Wp^T + bias  (64-row tiles)
    hipLaunchKernelGGL(gemm_proj, dim3(kDIM / 64, BN / 64), dim3(256), 0, stream,
                       Ab, wpb, b_proj, out);
}

// Round 4
// 177.826 us; speedup vs baseline: 1.0961x; 1.0961x over previous
//
#include <hip/hip_runtime.h>
#include <hip/hip_bf16.h>

// CrossAttention MI355X — Round 14.
//  - attn v8: P never touches LDS — after S^T, cvt_pk pairs + 4x
//    v_permlane32_swap_b32 build the PV B-fragments in-register (T12).
//    Removes 4 ds_write_b64 + 2 ds_read_b128 per wave-iter (~29% of the
//    LDS-pipe load; attn measured LDS-throughput-bound, R13 post-mortem).
//    Keeps T1 XCD remap (time-neutral, FETCH 69.7->12.3 MB).
//  - GEMMs reverted verbatim to known-good forms (R13's dbuf+T1 cost 16us:
//    LDS doubling halved blocks/CU and killed implicit cross-block overlap).
// Reference quirk: k = v = kv[:,:,0] -> only W_kv rows [0,1024) matter.

typedef __bf16 bf16x8 __attribute__((ext_vector_type(8)));
typedef float f32x4 __attribute__((ext_vector_type(4)));
typedef float f32x16 __attribute__((ext_vector_type(16)));

static constexpr int kDIM = 1024;
static constexpr float kLog2e = 1.4426950408889634f;

__device__ inline unsigned short f2bf(float f) {      // RNE
    union { float f; unsigned int u; } v; v.f = f;
    return (unsigned short)((v.u + 0x7FFFu + ((v.u >> 16) & 1u)) >> 16);
}

// single-instruction bf16 pair-pack: low16 = bf16(a), high16 = bf16(b)
__device__ inline unsigned int cvtpk2bf(float a, float b) {
    unsigned int r;
    asm("v_cvt_pk_bf16_f32 %0, %1, %2" : "=v"(r) : "v"(a), "v"(b));
    return r;
}

// async global->LDS, 16 B per lane; LDS dest = wave-uniform base + lane*16
__device__ inline void gload_lds16(const unsigned short* g, unsigned short* l) {
    __builtin_amdgcn_global_load_lds(
        (const __attribute__((address_space(1))) unsigned int*)g,
        (__attribute__((address_space(3))) unsigned int*)l, 16, 0, 0);
}

// ---------------------------------------------------------------------------
// Single cast kernel (unchanged).
// ---------------------------------------------------------------------------
__global__ __launch_bounds__(256) void cast_all(
    const float* __restrict__ x, const float* __restrict__ ctx,
    const float* __restrict__ wq, const float* __restrict__ wkv,
    const float* __restrict__ wp,
    unsigned short* __restrict__ xb, unsigned short* __restrict__ cb,
    unsigned short* __restrict__ wqb, unsigned short* __restrict__ wkb,
    unsigned short* __restrict__ wpb)
{
    int j = blockIdx.x * 256 + threadIdx.x;   // float4 index
    const float* s; unsigned short* d;
    if (j < 1048576)                      { s = x;   d = xb;  }
    else if ((j -= 1048576) < 1048576)    { s = ctx; d = cb;  }
    else if ((j -= 1048576) < 262144)     { s = wq;  d = wqb; }
    else if ((j -= 262144) < 262144)      { s = wkv; d = wkb; }
    else if ((j -= 262144) < 262144)      { s = wp;  d = wpb; }
    else return;
    float4 f = ((const float4*)s)[j];
    ushort4 o;
    o.x = f2bf(f.x); o.y = f2bf(f.y); o.z = f2bf(f.z); o.w = f2bf(f.w);
    ((ushort4*)d)[j] = o;
}

// ---------------------------------------------------------------------------
// Fused Q/K projection GEMM: 128(m)x64(n) tile, 256 thr (2x2 waves of 64x32),
// BK=64, XOR-swizzled global_load_lds staging, grid (16,32,2) = 1024 blocks.
// (verbatim R12 known-good form)
// ---------------------------------------------------------------------------
__global__ __launch_bounds__(256, 4) void gemm_qk(
    const unsigned short* __restrict__ xb, const unsigned short* __restrict__ cb,
    const unsigned short* __restrict__ Wq, const unsigned short* __restrict__ Wkv,
    unsigned short* __restrict__ Qb, unsigned short* __restrict__ Kb,
    unsigned short* __restrict__ Ktb, float qscale, int Mctx)
{
    __shared__ unsigned short As[128 * 64];
    __shared__ unsigned short Bs[64 * 64];
    const int z = blockIdx.z;
    const unsigned short* A  = z ? cb : xb;
    const unsigned short* Bw = z ? Wkv : Wq;
    unsigned short* Cb = z ? Kb : Qb;
    const float scale = z ? 1.0f : qscale;

    const int tid = threadIdx.x;
    const int wave = tid >> 6, lane = tid & 63;
    const int g = lane >> 4, c = lane & 15;
    const int wm = (wave & 1) * 64, wn = (wave >> 1) * 32;
    const int bm = blockIdx.y * 128, bn = blockIdx.x * 64;

    const int srow = lane >> 3;
    const int scolsw = ((lane & 7) ^ (srow & 7)) * 8;   // swizzled source col
    const int x7 = c & 7;                               // frag-read XOR term

    f32x4 acc[4][2];
    #pragma unroll
    for (int i = 0; i < 4; ++i)
        #pragma unroll
        for (int j = 0; j < 2; ++j)
            acc[i][j] = (f32x4){0.f, 0.f, 0.f, 0.f};

    for (int k0 = 0; k0 < kDIM; k0 += 64) {
        __syncthreads();
        #pragma unroll
        for (int t = 0; t < 4; ++t) {                 // A: 16 chunks
            const int chunk = wave * 4 + t;
            gload_lds16(A + (size_t)(bm + chunk * 8 + srow) * kDIM + k0 + scolsw,
                        &As[chunk * 512]);
        }
        #pragma unroll
        for (int t = 0; t < 2; ++t) {                 // B: 8 chunks
            const int chunk = wave * 2 + t;
            gload_lds16(Bw + (size_t)(bn + chunk * 8 + srow) * kDIM + k0 + scolsw,
                        &Bs[chunk * 512]);
        }
        __syncthreads();
        #pragma unroll
        for (int kc = 0; kc < 2; ++kc) {
            bf16x8 af[4], bfr[2];
            #pragma unroll
            for (int i = 0; i < 4; ++i)
                af[i] = *(const bf16x8*)&As[(wm + i * 16 + c) * 64 +
                                            ((kc * 4 + g) ^ x7) * 8];
            #pragma unroll
            for (int j = 0; j < 2; ++j)
                bfr[j] = *(const bf16x8*)&Bs[(wn + j * 16 + c) * 64 +
                                             ((kc * 4 + g) ^ x7) * 8];
            #pragma unroll
            for (int i = 0; i < 4; ++i)
                #pragma unroll
                for (int j = 0; j < 2; ++j)
                    acc[i][j] = __builtin_amdgcn_mfma_f32_16x16x32_bf16(
                        af[i], bfr[j], acc[i][j], 0, 0, 0);
        }
    }

    #pragma unroll
    for (int i = 0; i < 4; ++i) {
        #pragma unroll
        for (int j = 0; j < 2; ++j) {
            const int r0 = bm + wm + i * 16 + 4 * g;
            const int cc = bn + wn + j * 16 + c;
            float v0 = acc[i][j][0] * scale;
            float v1 = acc[i][j][1] * scale;
            float v2 = acc[i][j][2] * scale;
            float v3 = acc[i][j][3] * scale;
            Cb[(size_t)(r0 + 0) * kDIM + cc] = f2bf(v0);
            Cb[(size_t)(r0 + 1) * kDIM + cc] = f2bf(v1);
            Cb[(size_t)(r0 + 2) * kDIM + cc] = f2bf(v2);
            Cb[(size_t)(r0 + 3) * kDIM + cc] = f2bf(v3);
            if (z) {
                const int bb = r0 / Mctx, n0 = r0 % Mctx;
                const int hh = cc >> 6, d = cc & 63;
                ushort4 pk;
                pk.x = f2bf(v0); pk.y = f2bf(v1); pk.z = f2bf(v2); pk.w = f2bf(v3);
                *(ushort4*)&Ktb[((size_t)((bb * 16 + hh) * 64 + d)) * Mctx + n0] = pk;
            }
        }
    }
}

// ---------------------------------------------------------------------------
// Proj GEMM: 64x64 tiles, grid (16,64) = 1024 blocks, 256 thr, BK=64,
// XOR-swizzled DMA staging. (verbatim R10 known-good form)
// ---------------------------------------------------------------------------
__global__ __launch_bounds__(256, 4) void gemm_proj(
    const unsigned short* __restrict__ Ab, const unsigned short* __restrict__ Wp,
    const float* __restrict__ bias, float* __restrict__ out)
{
    __shared__ unsigned short As[64 * 64];
    __shared__ unsigned short Bs[64 * 64];
    const int tid = threadIdx.x;
    const int wave = tid >> 6, lane = tid & 63;
    const int g = lane >> 4, c = lane & 15;
    const int wm = (wave & 1) * 32, wn = (wave >> 1) * 32;
    const int bm = blockIdx.y * 64, bn = blockIdx.x * 64;

    const int srow = lane >> 3;
    const int scolsw = ((lane & 7) ^ (srow & 7)) * 8;
    const int x7 = c & 7;

    f32x4 acc[2][2];
    #pragma unroll
    for (int i = 0; i < 2; ++i)
        #pragma unroll
        for (int j = 0; j < 2; ++j)
            acc[i][j] = (f32x4){0.f, 0.f, 0.f, 0.f};

    for (int k0 = 0; k0 < kDIM; k0 += 64) {
        __syncthreads();
        #pragma unroll
        for (int t = 0; t < 2; ++t) {
            const int chunk = wave * 2 + t;              // 0..7
            const int row = chunk * 8 + srow;
            gload_lds16(Ab + (size_t)(bm + row) * kDIM + k0 + scolsw, &As[chunk * 512]);
            gload_lds16(Wp + (size_t)(bn + row) * kDIM + k0 + scolsw, &Bs[chunk * 512]);
        }
        __syncthreads();
        #pragma unroll
        for (int kc = 0; kc < 2; ++kc) {
            bf16x8 af[2], bfr[2];
            #pragma unroll
            for (int i = 0; i < 2; ++i)
                af[i] = *(const bf16x8*)&As[(wm + i * 16 + c) * 64 +
                                            ((kc * 4 + g) ^ x7) * 8];
            #pragma unroll
            for (int j = 0; j < 2; ++j)
                bfr[j] = *(const bf16x8*)&Bs[(wn + j * 16 + c) * 64 +
                                             ((kc * 4 + g) ^ x7) * 8];
            #pragma unroll
            for (int i = 0; i < 2; ++i)
                #pragma unroll
                for (int j = 0; j < 2; ++j)
                    acc[i][j] = __builtin_amdgcn_mfma_f32_16x16x32_bf16(
                        af[i], bfr[j], acc[i][j], 0, 0, 0);
        }
    }

    #pragma unroll
    for (int i = 0; i < 2; ++i) {
        #pragma unroll
        for (int j = 0; j < 2; ++j) {
            const int r0 = bm + wm + i * 16 + 4 * g;
            const int cc = bn + wn + j * 16 + c;
            const float bv = bias[cc];
            #pragma unroll
            for (int ii = 0; ii < 4; ++ii)
                out[(size_t)(r0 + ii) * kDIM + cc] = acc[i][j][ii] + bv;
        }
    }
}

// ---------------------------------------------------------------------------
// Flash attention v8: v7 (T14 reg prefetch + T1 XCD remap) with P built
// in-register: cvt_pk pairs + v_permlane32_swap_b32 produce the PV
// B-fragments directly (no Ps LDS buffer, no P write/read through LDS).
// 512 threads = 8 waves = 4 q-strips x 2 key-halves, 32x32x16 MFMA.
// ---------------------------------------------------------------------------
__global__ __launch_bounds__(512, 4) void attn_mfma_v8(
    const unsigned short* __restrict__ Q,   // [B*N][1024]
    const unsigned short* __restrict__ K,   // [B*M][1024]
    const unsigned short* __restrict__ Kt,  // [(B*16+h)*64+d][M]
    unsigned short* __restrict__ O, int N, int M)
{
    __shared__ unsigned short smem[18432];        // 36,864 B (epilogue Om needs it)
    unsigned short* Ks  = smem;                   // [64][72]
    unsigned short* Kts = smem + 64 * 72;         // [64][72]

    // T1: bijective chunked XCD remap (512 blocks, chunk = 64/XCD).
    const int lin  = blockIdx.x + 16 * (blockIdx.y + 16 * blockIdx.z);
    const int orig = (lin & 7) * 64 + (lin >> 3);
    const int q0 = (orig & 15) * 128;
    const int h  = (orig >> 4) & 15;
    const int b  = orig >> 8;

    const int tid = threadIdx.x;
    const int w = tid >> 6, lane = tid & 63;
    const int strip = w >> 1, kh = w & 1;
    const int ql = lane & 31, l5 = lane >> 5;

    const unsigned short* Qrow = Q + (size_t)(b * N + q0 + strip * 32 + ql) * kDIM + h * 64;
    const unsigned short* Kb = K + (size_t)b * M * kDIM + h * 64;
    const unsigned short* Ktb = Kt + (size_t)((b * 16 + h) * 64) * M;

    bf16x8 bq[4];
    #pragma unroll
    for (int kc = 0; kc < 4; ++kc)
        bq[kc] = *(const bf16x8*)(Qrow + kc * 16 + l5 * 8);

    f32x16 ot[2];
    #pragma unroll
    for (int dt = 0; dt < 2; ++dt)
        #pragma unroll
        for (int r = 0; r < 16; ++r) ot[dt][r] = 0.f;
    float lac = 0.f;

    const int srow = tid >> 3, scol = (tid & 7) * 8;

    // T14: prefetch first K/Kt tile into registers before the loop.
    uint4 rk  = *(const uint4*)(Kb  + (size_t)srow * kDIM + scol);
    uint4 rkt = *(const uint4*)(Ktb + (size_t)srow * M + scol);

    for (int k0 = 0; k0 < M; k0 += 64) {
        __syncthreads();                          // prev-iter LDS reads done
        *(uint4*)&Ks[srow * 72 + scol]  = rk;
        *(uint4*)&Kts[srow * 72 + scol] = rkt;
        __syncthreads();

        // Issue next tile's global loads now; latency hides under compute.
        if (k0 + 64 < M) {
            rk  = *(const uint4*)(Kb  + (size_t)(k0 + 64 + srow) * kDIM + scol);
            rkt = *(const uint4*)(Ktb + (size_t)srow * M + (k0 + 64) + scol);
        }

        // S^T (32 keys of this wave's half x 32 q): A = K, B = Q.
        // Lane (ql,l5) holds st[r] = S[key=(r&3)+8*(r>>2)+4*l5][q=ql].
        f32x16 st;
        #pragma unroll
        for (int r = 0; r < 16; ++r) st[r] = 0.f;
        #pragma unroll
        for (int kc = 0; kc < 4; ++kc) {
            bf16x8 ak = *(const bf16x8*)&Ks[(kh * 32 + ql) * 72 + kc * 16 + l5 * 8];
            st = __builtin_amdgcn_mfma_f32_32x32x16_bf16(ak, bq[kc], st, 0, 0, 0);
        }

        // p = 2^s; per-lane partial row sums; pack key-pairs into dwords.
        // dw[p] = keys (2p&3, 2p&3+1) + 8*(p>>1) + 4*l5 paired for query ql.
        float pr[16];
        #pragma unroll
        for (int r = 0; r < 16; ++r) {
            pr[r] = __builtin_amdgcn_exp2f(st[r]);
            lac += pr[r];
        }
        unsigned int dw[8];
        #pragma unroll
        for (int p = 0; p < 8; ++p) dw[p] = cvtpk2bf(pr[2 * p], pr[2 * p + 1]);

        // T12: in-register P redistribution. PV B-fragment needs keys
        // kc2*16 + l5*8 + e at query ql. One permlane32_swap of (dwA,dwA+2)
        // yields two fragment dwords: [A.lo|B.lo] and [A.hi|B.hi].
        auto s02 = __builtin_amdgcn_permlane32_swap(dw[0], dw[2], false, false);
        auto s13 = __builtin_amdgcn_permlane32_swap(dw[1], dw[3], false, false);
        auto s46 = __builtin_amdgcn_permlane32_swap(dw[4], dw[6], false, false);
        auto s57 = __builtin_amdgcn_permlane32_swap(dw[5], dw[7], false, false);
        union BP { unsigned int u[4]; bf16x8 v; };
        BP b0, b1;
        b0.u[0] = s02[0]; b0.u[1] = s13[0]; b0.u[2] = s02[1]; b0.u[3] = s13[1];
        b1.u[0] = s46[0]; b1.u[1] = s57[0]; b1.u[2] = s46[1]; b1.u[3] = s57[1];
        bf16x8 bp[2] = { b0.v, b1.v };

        // O^T += V^T . P  (A = V^T from Kts, B = P in-register)
        #pragma unroll
        for (int kc2 = 0; kc2 < 2; ++kc2) {
            #pragma unroll
            for (int dt = 0; dt < 2; ++dt) {
                bf16x8 av = *(const bf16x8*)&Kts[(dt * 32 + ql) * 72 + kh * 32 + kc2 * 16 + l5 * 8];
                ot[dt] = __builtin_amdgcn_mfma_f32_32x32x16_bf16(av, bp[kc2], ot[dt], 0, 0, 0);
            }
        }
    }

    // Merge the two key-halves via LDS, normalize, store.
    float lw = lac + __shfl_xor(lac, 32);     // full half-sum for this q
    float* Om = (float*)smem;                  // [128][68] fp32
    float* Lm = Om + 128 * 68;                 // [128]
    const int qi = strip * 32 + ql;

    __syncthreads();                           // all LDS reads of last iter done
    if (kh == 1) {
        #pragma unroll
        for (int dt = 0; dt < 2; ++dt)
            #pragma unroll
            for (int rr = 0; rr < 4; ++rr)
                *(f32x4*)&Om[qi * 68 + dt * 32 + 8 * rr + 4 * l5] =
                    (f32x4){ot[dt][4 * rr], ot[dt][4 * rr + 1],
                            ot[dt][4 * rr + 2], ot[dt][4 * rr + 3]};
        if (l5 == 0) Lm[qi] = lw;
    }
    __syncthreads();
    if (kh == 0) {
        const float inv = 1.0f / (lw + Lm[qi]);
        unsigned short* Ob = O + (size_t)(b * N + q0 + qi) * kDIM + h * 64;
        #pragma unroll
        for (int dt = 0; dt < 2; ++dt)
            #pragma unroll
            for (int rr = 0; rr < 4; ++rr) {
                f32x4 pv = *(const f32x4*)&Om[qi * 68 + dt * 32 + 8 * rr + 4 * l5];
                ushort4 u;
                u.x = f2bf((ot[dt][4 * rr]     + pv[0]) * inv);
                u.y = f2bf((ot[dt][4 * rr + 1] + pv[1]) * inv);
                u.z = f2bf((ot[dt][4 * rr + 2] + pv[2]) * inv);
                u.w = f2bf((ot[dt][4 * rr + 3] + pv[3]) * inv);
                *(ushort4*)(Ob + dt * 32 + 8 * rr + 4 * l5) = u;
            }
    }
}

// ---------------------------------------------------------------------------
extern "C" void kernel_launch(void* const* d_in, const int* in_sizes, int n_in,
                              void* d_out, int out_size, void* d_ws, size_t ws_size,
                              hipStream_t stream)
{
    const float* x      = (const float*)d_in[0];
    const float* ctxp   = (const float*)d_in[1];
    const float* W_q    = (const float*)d_in[2];
    const float* W_kv   = (const float*)d_in[3];
    const float* W_proj = (const float*)d_in[4];
    const float* b_proj = (const float*)d_in[5];
    float* out = (float*)d_out;

    const int B = 2, N = 2048, M = 2048;
    const int BN = B * N;        // 4096
    const int SQ = kDIM * kDIM;  // 1M

    unsigned short* p = (unsigned short*)d_ws;
    unsigned short* xb  = p; p += (size_t)BN * kDIM;   // reused as Ab
    unsigned short* cb  = p; p += (size_t)BN * kDIM;
    unsigned short* wqb = p; p += SQ;
    unsigned short* wkb = p; p += SQ;
    unsigned short* wpb = p; p += SQ;
    unsigned short* Qb  = p; p += (size_t)BN * kDIM;
    unsigned short* Kb  = p; p += (size_t)BN * kDIM;
    unsigned short* Ktb = p; p += (size_t)BN * kDIM;
    unsigned short* Ab  = xb;    // xb dead after gemm_qk

    // 1) fp32 -> bf16 for all inputs
    hipLaunchKernelGGL(cast_all, dim3(11264), dim3(256), 0, stream,
                       x, ctxp, W_q, W_kv, W_proj, xb, cb, wqb, wkb, wpb);
    // 2) z=0: Q = (0.125*log2e) * x @ Wq^T ; z=1: K(=V) = ctx @ Wkv^T (+ K^T)
    hipLaunchKernelGGL(gemm_qk, dim3(kDIM / 64, BN / 128, 2), dim3(256), 0, stream,
                       xb, cb, wqb, wkb, Qb, Kb, Ktb, 0.125f * kLog2e, M);
    // 3) A = softmax(Q K^T) V
    hipLaunchKernelGGL(attn_mfma_v8, dim3(N / 128, 16, B), dim3(512), 0, stream,
                       Qb, Kb, Ktb, Ab, N, M);
    // 4) out = A @ Wp^T + bias
    hipLaunchKernelGGL(gemm_proj, dim3(kDIM / 64, BN / 64), dim3(256), 0, stream,
                       Ab, wpb, b_proj, out);
}

// Round 5
// 175.689 us; speedup vs baseline: 1.1094x; 1.0122x over previous
//
#include <hip/hip_runtime.h>
#include <hip/hip_bf16.h>

// CrossAttention MI355X — Round 15.
//  - gemm_qk: 128x128 tile @ 512 threads (8 waves of 64x32, acc 4x2).
//    Grid (8,32,2)=512 blocks x 8 waves = 16 waves/CU — same wave count as
//    the 128x64@1024-block version but 1.5x less staging traffic per output
//    (2 B/elem/K-step vs 3). Same XOR-swizzle, same 2-barrier K-loop.
//    (R12's proj regression at 512 blocks was 8 waves/CU; this keeps 16.)
//  - attn v8 (in-register P via cvt_pk+permlane32_swap, bank-conflicts = 0),
//    gemm_proj 64x64, cast_all: unchanged from R14.
// Reference quirk: k = v = kv[:,:,0] -> only W_kv rows [0,1024) matter.

typedef __bf16 bf16x8 __attribute__((ext_vector_type(8)));
typedef float f32x4 __attribute__((ext_vector_type(4)));
typedef float f32x16 __attribute__((ext_vector_type(16)));

static constexpr int kDIM = 1024;
static constexpr float kLog2e = 1.4426950408889634f;

__device__ inline unsigned short f2bf(float f) {      // RNE
    union { float f; unsigned int u; } v; v.f = f;
    return (unsigned short)((v.u + 0x7FFFu + ((v.u >> 16) & 1u)) >> 16);
}

// single-instruction bf16 pair-pack: low16 = bf16(a), high16 = bf16(b)
__device__ inline unsigned int cvtpk2bf(float a, float b) {
    unsigned int r;
    asm("v_cvt_pk_bf16_f32 %0, %1, %2" : "=v"(r) : "v"(a), "v"(b));
    return r;
}

// async global->LDS, 16 B per lane; LDS dest = wave-uniform base + lane*16
__device__ inline void gload_lds16(const unsigned short* g, unsigned short* l) {
    __builtin_amdgcn_global_load_lds(
        (const __attribute__((address_space(1))) unsigned int*)g,
        (__attribute__((address_space(3))) unsigned int*)l, 16, 0, 0);
}

// ---------------------------------------------------------------------------
// Single cast kernel (unchanged).
// ---------------------------------------------------------------------------
__global__ __launch_bounds__(256) void cast_all(
    const float* __restrict__ x, const float* __restrict__ ctx,
    const float* __restrict__ wq, const float* __restrict__ wkv,
    const float* __restrict__ wp,
    unsigned short* __restrict__ xb, unsigned short* __restrict__ cb,
    unsigned short* __restrict__ wqb, unsigned short* __restrict__ wkb,
    unsigned short* __restrict__ wpb)
{
    int j = blockIdx.x * 256 + threadIdx.x;   // float4 index
    const float* s; unsigned short* d;
    if (j < 1048576)                      { s = x;   d = xb;  }
    else if ((j -= 1048576) < 1048576)    { s = ctx; d = cb;  }
    else if ((j -= 1048576) < 262144)     { s = wq;  d = wqb; }
    else if ((j -= 262144) < 262144)      { s = wkv; d = wkb; }
    else if ((j -= 262144) < 262144)      { s = wp;  d = wpb; }
    else return;
    float4 f = ((const float4*)s)[j];
    ushort4 o;
    o.x = f2bf(f.x); o.y = f2bf(f.y); o.z = f2bf(f.z); o.w = f2bf(f.w);
    ((ushort4*)d)[j] = o;
}

// ---------------------------------------------------------------------------
// Fused Q/K projection GEMM: 128(m)x128(n) tile, 512 thr (8 waves of 64x32),
// BK=64, XOR-swizzled global_load_lds staging, grid (8,32,2) = 512 blocks.
// z=0: Qb = qscale * x @ Wq^T ; z=1: Kb = ctx @ Wkv^T (+ K^T layout Ktb).
// LDS layout: elem(row, physcg*8..+7), physcg = logicalcg ^ (row&7).
// ---------------------------------------------------------------------------
__global__ __launch_bounds__(512, 4) void gemm_qk(
    const unsigned short* __restrict__ xb, const unsigned short* __restrict__ cb,
    const unsigned short* __restrict__ Wq, const unsigned short* __restrict__ Wkv,
    unsigned short* __restrict__ Qb, unsigned short* __restrict__ Kb,
    unsigned short* __restrict__ Ktb, float qscale, int Mctx)
{
    __shared__ unsigned short As[128 * 64];
    __shared__ unsigned short Bs[128 * 64];
    const int z = blockIdx.z;
    const unsigned short* A  = z ? cb : xb;
    const unsigned short* Bw = z ? Wkv : Wq;
    unsigned short* Cb = z ? Kb : Qb;
    const float scale = z ? 1.0f : qscale;

    const int tid = threadIdx.x;
    const int wave = tid >> 6, lane = tid & 63;
    const int g = lane >> 4, c = lane & 15;
    const int wm = (wave >> 2) * 64, wn = (wave & 3) * 32;
    const int bm = blockIdx.y * 128, bn = blockIdx.x * 128;

    const int srow = lane >> 3;
    const int scolsw = ((lane & 7) ^ (srow & 7)) * 8;   // swizzled source col
    const int x7 = c & 7;                               // frag-read XOR term

    f32x4 acc[4][2];
    #pragma unroll
    for (int i = 0; i < 4; ++i)
        #pragma unroll
        for (int j = 0; j < 2; ++j)
            acc[i][j] = (f32x4){0.f, 0.f, 0.f, 0.f};

    for (int k0 = 0; k0 < kDIM; k0 += 64) {
        __syncthreads();
        #pragma unroll
        for (int t = 0; t < 2; ++t) {                 // A: 16 chunks, 2/wave
            const int chunk = wave * 2 + t;
            gload_lds16(A + (size_t)(bm + chunk * 8 + srow) * kDIM + k0 + scolsw,
                        &As[chunk * 512]);
        }
        #pragma unroll
        for (int t = 0; t < 2; ++t) {                 // B: 16 chunks, 2/wave
            const int chunk = wave * 2 + t;
            gload_lds16(Bw + (size_t)(bn + chunk * 8 + srow) * kDIM + k0 + scolsw,
                        &Bs[chunk * 512]);
        }
        __syncthreads();
        #pragma unroll
        for (int kc = 0; kc < 2; ++kc) {
            bf16x8 af[4], bfr[2];
            #pragma unroll
            for (int i = 0; i < 4; ++i)
                af[i] = *(const bf16x8*)&As[(wm + i * 16 + c) * 64 +
                                            ((kc * 4 + g) ^ x7) * 8];
            #pragma unroll
            for (int j = 0; j < 2; ++j)
                bfr[j] = *(const bf16x8*)&Bs[(wn + j * 16 + c) * 64 +
                                             ((kc * 4 + g) ^ x7) * 8];
            #pragma unroll
            for (int i = 0; i < 4; ++i)
                #pragma unroll
                for (int j = 0; j < 2; ++j)
                    acc[i][j] = __builtin_amdgcn_mfma_f32_16x16x32_bf16(
                        af[i], bfr[j], acc[i][j], 0, 0, 0);
        }
    }

    #pragma unroll
    for (int i = 0; i < 4; ++i) {
        #pragma unroll
        for (int j = 0; j < 2; ++j) {
            const int r0 = bm + wm + i * 16 + 4 * g;
            const int cc = bn + wn + j * 16 + c;
            float v0 = acc[i][j][0] * scale;
            float v1 = acc[i][j][1] * scale;
            float v2 = acc[i][j][2] * scale;
            float v3 = acc[i][j][3] * scale;
            Cb[(size_t)(r0 + 0) * kDIM + cc] = f2bf(v0);
            Cb[(size_t)(r0 + 1) * kDIM + cc] = f2bf(v1);
            Cb[(size_t)(r0 + 2) * kDIM + cc] = f2bf(v2);
            Cb[(size_t)(r0 + 3) * kDIM + cc] = f2bf(v3);
            if (z) {
                const int bb = r0 / Mctx, n0 = r0 % Mctx;
                const int hh = cc >> 6, d = cc & 63;
                ushort4 pk;
                pk.x = f2bf(v0); pk.y = f2bf(v1); pk.z = f2bf(v2); pk.w = f2bf(v3);
                *(ushort4*)&Ktb[((size_t)((bb * 16 + hh) * 64 + d)) * Mctx + n0] = pk;
            }
        }
    }
}

// ---------------------------------------------------------------------------
// Proj GEMM: 64x64 tiles, grid (16,64) = 1024 blocks, 256 thr, BK=64,
// XOR-swizzled DMA staging. (verbatim R10 known-good form)
// ---------------------------------------------------------------------------
__global__ __launch_bounds__(256, 4) void gemm_proj(
    const unsigned short* __restrict__ Ab, const unsigned short* __restrict__ Wp,
    const float* __restrict__ bias, float* __restrict__ out)
{
    __shared__ unsigned short As[64 * 64];
    __shared__ unsigned short Bs[64 * 64];
    const int tid = threadIdx.x;
    const int wave = tid >> 6, lane = tid & 63;
    const int g = lane >> 4, c = lane & 15;
    const int wm = (wave & 1) * 32, wn = (wave >> 1) * 32;
    const int bm = blockIdx.y * 64, bn = blockIdx.x * 64;

    const int srow = lane >> 3;
    const int scolsw = ((lane & 7) ^ (srow & 7)) * 8;
    const int x7 = c & 7;

    f32x4 acc[2][2];
    #pragma unroll
    for (int i = 0; i < 2; ++i)
        #pragma unroll
        for (int j = 0; j < 2; ++j)
            acc[i][j] = (f32x4){0.f, 0.f, 0.f, 0.f};

    for (int k0 = 0; k0 < kDIM; k0 += 64) {
        __syncthreads();
        #pragma unroll
        for (int t = 0; t < 2; ++t) {
            const int chunk = wave * 2 + t;              // 0..7
            const int row = chunk * 8 + srow;
            gload_lds16(Ab + (size_t)(bm + row) * kDIM + k0 + scolsw, &As[chunk * 512]);
            gload_lds16(Wp + (size_t)(bn + row) * kDIM + k0 + scolsw, &Bs[chunk * 512]);
        }
        __syncthreads();
        #pragma unroll
        for (int kc = 0; kc < 2; ++kc) {
            bf16x8 af[2], bfr[2];
            #pragma unroll
            for (int i = 0; i < 2; ++i)
                af[i] = *(const bf16x8*)&As[(wm + i * 16 + c) * 64 +
                                            ((kc * 4 + g) ^ x7) * 8];
            #pragma unroll
            for (int j = 0; j < 2; ++j)
                bfr[j] = *(const bf16x8*)&Bs[(wn + j * 16 + c) * 64 +
                                             ((kc * 4 + g) ^ x7) * 8];
            #pragma unroll
            for (int i = 0; i < 2; ++i)
                #pragma unroll
                for (int j = 0; j < 2; ++j)
                    acc[i][j] = __builtin_amdgcn_mfma_f32_16x16x32_bf16(
                        af[i], bfr[j], acc[i][j], 0, 0, 0);
        }
    }

    #pragma unroll
    for (int i = 0; i < 2; ++i) {
        #pragma unroll
        for (int j = 0; j < 2; ++j) {
            const int r0 = bm + wm + i * 16 + 4 * g;
            const int cc = bn + wn + j * 16 + c;
            const float bv = bias[cc];
            #pragma unroll
            for (int ii = 0; ii < 4; ++ii)
                out[(size_t)(r0 + ii) * kDIM + cc] = acc[i][j][ii] + bv;
        }
    }
}

// ---------------------------------------------------------------------------
// Flash attention v8 (unchanged from R14): in-register P via cvt_pk +
// v_permlane32_swap_b32; T14 reg prefetch; T1 XCD remap.
// 512 threads = 8 waves = 4 q-strips x 2 key-halves, 32x32x16 MFMA.
// ---------------------------------------------------------------------------
__global__ __launch_bounds__(512, 4) void attn_mfma_v8(
    const unsigned short* __restrict__ Q,   // [B*N][1024]
    const unsigned short* __restrict__ K,   // [B*M][1024]
    const unsigned short* __restrict__ Kt,  // [(B*16+h)*64+d][M]
    unsigned short* __restrict__ O, int N, int M)
{
    __shared__ unsigned short smem[18432];        // 36,864 B (epilogue Om needs it)
    unsigned short* Ks  = smem;                   // [64][72]
    unsigned short* Kts = smem + 64 * 72;         // [64][72]

    // T1: bijective chunked XCD remap (512 blocks, chunk = 64/XCD).
    const int lin  = blockIdx.x + 16 * (blockIdx.y + 16 * blockIdx.z);
    const int orig = (lin & 7) * 64 + (lin >> 3);
    const int q0 = (orig & 15) * 128;
    const int h  = (orig >> 4) & 15;
    const int b  = orig >> 8;

    const int tid = threadIdx.x;
    const int w = tid >> 6, lane = tid & 63;
    const int strip = w >> 1, kh = w & 1;
    const int ql = lane & 31, l5 = lane >> 5;

    const unsigned short* Qrow = Q + (size_t)(b * N + q0 + strip * 32 + ql) * kDIM + h * 64;
    const unsigned short* Kb = K + (size_t)b * M * kDIM + h * 64;
    const unsigned short* Ktb = Kt + (size_t)((b * 16 + h) * 64) * M;

    bf16x8 bq[4];
    #pragma unroll
    for (int kc = 0; kc < 4; ++kc)
        bq[kc] = *(const bf16x8*)(Qrow + kc * 16 + l5 * 8);

    f32x16 ot[2];
    #pragma unroll
    for (int dt = 0; dt < 2; ++dt)
        #pragma unroll
        for (int r = 0; r < 16; ++r) ot[dt][r] = 0.f;
    float lac = 0.f;

    const int srow = tid >> 3, scol = (tid & 7) * 8;

    // T14: prefetch first K/Kt tile into registers before the loop.
    uint4 rk  = *(const uint4*)(Kb  + (size_t)srow * kDIM + scol);
    uint4 rkt = *(const uint4*)(Ktb + (size_t)srow * M + scol);

    for (int k0 = 0; k0 < M; k0 += 64) {
        __syncthreads();                          // prev-iter LDS reads done
        *(uint4*)&Ks[srow * 72 + scol]  = rk;
        *(uint4*)&Kts[srow * 72 + scol] = rkt;
        __syncthreads();

        // Issue next tile's global loads now; latency hides under compute.
        if (k0 + 64 < M) {
            rk  = *(const uint4*)(Kb  + (size_t)(k0 + 64 + srow) * kDIM + scol);
            rkt = *(const uint4*)(Ktb + (size_t)srow * M + (k0 + 64) + scol);
        }

        // S^T (32 keys of this wave's half x 32 q): A = K, B = Q.
        // Lane (ql,l5) holds st[r] = S[key=(r&3)+8*(r>>2)+4*l5][q=ql].
        f32x16 st;
        #pragma unroll
        for (int r = 0; r < 16; ++r) st[r] = 0.f;
        #pragma unroll
        for (int kc = 0; kc < 4; ++kc) {
            bf16x8 ak = *(const bf16x8*)&Ks[(kh * 32 + ql) * 72 + kc * 16 + l5 * 8];
            st = __builtin_amdgcn_mfma_f32_32x32x16_bf16(ak, bq[kc], st, 0, 0, 0);
        }

        // p = 2^s; per-lane partial row sums; pack key-pairs into dwords.
        float pr[16];
        #pragma unroll
        for (int r = 0; r < 16; ++r) {
            pr[r] = __builtin_amdgcn_exp2f(st[r]);
            lac += pr[r];
        }
        unsigned int dw[8];
        #pragma unroll
        for (int p = 0; p < 8; ++p) dw[p] = cvtpk2bf(pr[2 * p], pr[2 * p + 1]);

        // T12: in-register P redistribution. PV B-fragment needs keys
        // kc2*16 + l5*8 + e at query ql. One permlane32_swap of (dwA,dwA+2)
        // yields two fragment dwords: [A.lo|B.lo] and [A.hi|B.hi].
        auto s02 = __builtin_amdgcn_permlane32_swap(dw[0], dw[2], false, false);
        auto s13 = __builtin_amdgcn_permlane32_swap(dw[1], dw[3], false, false);
        auto s46 = __builtin_amdgcn_permlane32_swap(dw[4], dw[6], false, false);
        auto s57 = __builtin_amdgcn_permlane32_swap(dw[5], dw[7], false, false);
        union BP { unsigned int u[4]; bf16x8 v; };
        BP b0, b1;
        b0.u[0] = s02[0]; b0.u[1] = s13[0]; b0.u[2] = s02[1]; b0.u[3] = s13[1];
        b1.u[0] = s46[0]; b1.u[1] = s57[0]; b1.u[2] = s46[1]; b1.u[3] = s57[1];
        bf16x8 bp[2] = { b0.v, b1.v };

        // O^T += V^T . P  (A = V^T from Kts, B = P in-register)
        #pragma unroll
        for (int kc2 = 0; kc2 < 2; ++kc2) {
            #pragma unroll
            for (int dt = 0; dt < 2; ++dt) {
                bf16x8 av = *(const bf16x8*)&Kts[(dt * 32 + ql) * 72 + kh * 32 + kc2 * 16 + l5 * 8];
                ot[dt] = __builtin_amdgcn_mfma_f32_32x32x16_bf16(av, bp[kc2], ot[dt], 0, 0, 0);
            }
        }
    }

    // Merge the two key-halves via LDS, normalize, store.
    float lw = lac + __shfl_xor(lac, 32);     // full half-sum for this q
    float* Om = (float*)smem;                  // [128][68] fp32
    float* Lm = Om + 128 * 68;                 // [128]
    const int qi = strip * 32 + ql;

    __syncthreads();                           // all LDS reads of last iter done
    if (kh == 1) {
        #pragma unroll
        for (int dt = 0; dt < 2; ++dt)
            #pragma unroll
            for (int rr = 0; rr < 4; ++rr)
                *(f32x4*)&Om[qi * 68 + dt * 32 + 8 * rr + 4 * l5] =
                    (f32x4){ot[dt][4 * rr], ot[dt][4 * rr + 1],
                            ot[dt][4 * rr + 2], ot[dt][4 * rr + 3]};
        if (l5 == 0) Lm[qi] = lw;
    }
    __syncthreads();
    if (kh == 0) {
        const float inv = 1.0f / (lw + Lm[qi]);
        unsigned short* Ob = O + (size_t)(b * N + q0 + qi) * kDIM + h * 64;
        #pragma unroll
        for (int dt = 0; dt < 2; ++dt)
            #pragma unroll
            for (int rr = 0; rr < 4; ++rr) {
                f32x4 pv = *(const f32x4*)&Om[qi * 68 + dt * 32 + 8 * rr + 4 * l5];
                ushort4 u;
                u.x = f2bf((ot[dt][4 * rr]     + pv[0]) * inv);
                u.y = f2bf((ot[dt][4 * rr + 1] + pv[1]) * inv);
                u.z = f2bf((ot[dt][4 * rr + 2] + pv[2]) * inv);
                u.w = f2bf((ot[dt][4 * rr + 3] + pv[3]) * inv);
                *(ushort4*)(Ob + dt * 32 + 8 * rr + 4 * l5) = u;
            }
    }
}

// ---------------------------------------------------------------------------
extern "C" void kernel_launch(void* const* d_in, const int* in_sizes, int n_in,
                              void* d_out, int out_size, void* d_ws, size_t ws_size,
                              hipStream_t stream)
{
    const float* x      = (const float*)d_in[0];
    const float* ctxp   = (const float*)d_in[1];
    const float* W_q    = (const float*)d_in[2];
    const float* W_kv   = (const float*)d_in[3];
    const float* W_proj = (const float*)d_in[4];
    const float* b_proj = (const float*)d_in[5];
    float* out = (float*)d_out;

    const int B = 2, N = 2048, M = 2048;
    const int BN = B * N;        // 4096
    const int SQ = kDIM * kDIM;  // 1M

    unsigned short* p = (unsigned short*)d_ws;
    unsigned short* xb  = p; p += (size_t)BN * kDIM;   // reused as Ab
    unsigned short* cb  = p; p += (size_t)BN * kDIM;
    unsigned short* wqb = p; p += SQ;
    unsigned short* wkb = p; p += SQ;
    unsigned short* wpb = p; p += SQ;
    unsigned short* Qb  = p; p += (size_t)BN * kDIM;
    unsigned short* Kb  = p; p += (size_t)BN * kDIM;
    unsigned short* Ktb = p; p += (size_t)BN * kDIM;
    unsigned short* Ab  = xb;    // xb dead after gemm_qk

    // 1) fp32 -> bf16 for all inputs
    hipLaunchKernelGGL(cast_all, dim3(11264), dim3(256), 0, stream,
                       x, ctxp, W_q, W_kv, W_proj, xb, cb, wqb, wkb, wpb);
    // 2) z=0: Q = (0.125*log2e) * x @ Wq^T ; z=1: K(=V) = ctx @ Wkv^T (+ K^T)
    //    128x128 tiles @ 512 threads
    hipLaunchKernelGGL(gemm_qk, dim3(kDIM / 128, BN / 128, 2), dim3(512), 0, stream,
                       xb, cb, wqb, wkb, Qb, Kb, Ktb, 0.125f * kLog2e, M);
    // 3) A = softmax(Q K^T) V
    hipLaunchKernelGGL(attn_mfma_v8, dim3(N / 128, 16, B), dim3(512), 0, stream,
                       Qb, Kb, Ktb, Ab, N, M);
    // 4) out = A @ Wp^T + bias
    hipLaunchKernelGGL(gemm_proj, dim3(kDIM / 64, BN / 64), dim3(256), 0, stream,
                       Ab, wpb, b_proj, out);
}